// Round 12
// baseline (508.554 us; speedup 1.0000x reference)
//
#include <hip/hip_runtime.h>

// BiMambaBlock on gfx950. Inputs fp32 (bf16-valued), output fp32.
// Round 12 diff vs round 11: prepend hipMemsetAsync(d_ws, 0) so every call
// (first / graph replay / fresh) sees identical workspace state. Round 11
// showed first-launch-correct but consistent post-timing divergence (3.04)
// == result depended on ws entry contents (harness poisons 0xAA before timed
// launches). Audit found no read-before-write; memset makes entry state
// irrelevant either way (~30us for 134 MB). Pipeline otherwise identical:
//  - scan TCH=32/NCH=32 (3 waves/SIMD), GP=8 prefetch
//  - bf16 intermediates xz (MODE 3) and delta (MODE 2)
//  - register-prefetch pipelined GEMMs

typedef unsigned short u16;
typedef unsigned int u32;
typedef __bf16 bf16x8 __attribute__((ext_vector_type(8)));
typedef float f32x4 __attribute__((ext_vector_type(4)));
typedef u32 u32x4 __attribute__((ext_vector_type(4)));

#define L_SEQ 1024
#define DM 768
#define DI 1536
#define DS 16
#define DTR 48
#define M_TOK 2048
#define TCH 32
#define NCH (L_SEQ / TCH)  // 32
#define GP 8               // steps per load group in scan

__device__ __forceinline__ float bf2f(u16 u) {
  union { u32 i; float f; } v; v.i = ((u32)u) << 16; return v.f;
}
__device__ __forceinline__ u16 f2bf(float f) {
  union { float f; u32 i; } v; v.f = f;
  u32 r = v.i + 0x7fffu + ((v.i >> 16) & 1u);   // RNE
  return (u16)(r >> 16);
}

// ---------------- fp32 -> bf16 convert (GEMM weights) ----------------------
__launch_bounds__(256)
__global__ void k_cvt(const float* __restrict__ in, u16* __restrict__ out, int n) {
  const int i = blockIdx.x * 256 + threadIdx.x;
  if (i < n) out[i] = f2bf(in[i]);
}

// ---------------- LayerNorm ------------------------------------------------
__launch_bounds__(256)
__global__ void k_ln(const float* __restrict__ x, const float* __restrict__ g,
                     const float* __restrict__ b, u16* __restrict__ x0) {
  const int tok = blockIdx.x;
  const int tid = threadIdx.x;
  const float e0 = x[tok * DM + tid];
  const float e1 = x[tok * DM + tid + 256];
  const float e2 = x[tok * DM + tid + 512];
  float s = e0 + e1 + e2;
  float s2 = e0 * e0 + e1 * e1 + e2 * e2;
#pragma unroll
  for (int off = 1; off < 64; off <<= 1) {
    s += __shfl_xor(s, off, 64);
    s2 += __shfl_xor(s2, off, 64);
  }
  __shared__ float rs[4], rq[4];
  const int wave = tid >> 6, lane = tid & 63;
  if (lane == 0) { rs[wave] = s; rq[wave] = s2; }
  __syncthreads();
  s = rs[0] + rs[1] + rs[2] + rs[3];
  s2 = rq[0] + rq[1] + rq[2] + rq[3];
  const float mean = s * (1.0f / DM);
  const float var = s2 * (1.0f / DM) - mean * mean;
  const float inv = rsqrtf(var + 1e-5f);
  x0[tok * DM + tid]       = f2bf((e0 - mean) * inv * g[tid]       + b[tid]);
  x0[tok * DM + tid + 256] = f2bf((e1 - mean) * inv * g[tid + 256] + b[tid + 256]);
  x0[tok * DM + tid + 512] = f2bf((e2 - mean) * inv * g[tid + 512] + b[tid + 512]);
}

// ---------------- weight padding ------------------------------------------
__launch_bounds__(256)
__global__ void k_pad_xproj(const float* __restrict__ w0, const float* __restrict__ w1,
                            u16* __restrict__ o0, u16* __restrict__ o1) {
  const int dir = blockIdx.z;
  const float* w = dir ? w1 : w0;
  u16* o = dir ? o1 : o0;
  const int col = blockIdx.x * 256 + threadIdx.x;
  const int row = blockIdx.y;
  o[row * DI + col] = (row < 80) ? f2bf(w[row * DI + col]) : (u16)0;
}
__launch_bounds__(256)
__global__ void k_pad_dtw(const float* __restrict__ w0, const float* __restrict__ w1,
                          u16* __restrict__ o0, u16* __restrict__ o1) {
  const int dir = blockIdx.y;
  const float* w = dir ? w1 : w0;
  u16* o = dir ? o1 : o0;
  const int idx = blockIdx.x * 256 + threadIdx.x;
  const int row = idx >> 6, col = idx & 63;
  o[idx] = (col < DTR) ? f2bf(w[row * DTR + col]) : (u16)0;
}

// ---------------- GEMM: C[m,n] = sum_k A[m,k]*W[n,k], bf16 in -------------
// BM=128, BK=32, templated BN/WN. Register-prefetch pipeline, K % 64 == 0.
// MODE 0: fp32 C store.
// MODE 1: fp32 C store + bf16 aux[m*64+n] for n<64 (0 for n>=48).
// MODE 2: bf16 aux[m*N+n] = softplus(acc + bias[n]); no C store.
// MODE 3: bf16 aux[m*N+n] = acc; no C store.
template <int BN, int WN, int MODE>
__launch_bounds__(256)
__global__ void k_gemm(const u16* __restrict__ A0, const u16* __restrict__ A1,
                       const u16* __restrict__ W0, const u16* __restrict__ W1,
                       float* __restrict__ C0, float* __restrict__ C1,
                       const float* __restrict__ b0, const float* __restrict__ b1,
                       u16* __restrict__ aux0, u16* __restrict__ aux1,
                       int N, int K, int flip1) {
  constexpr int NWC = BN / WN;       // wave columns
  constexpr int FJ = WN / 16;        // n-frags per wave
  constexpr int CB = (BN * 32) / (256 * 8);  // B reg chunks per thread

  const int dir = blockIdx.z;
  const u16* A = dir ? A1 : A0;
  const u16* W = dir ? W1 : W0;
  float* C = dir ? C1 : C0;
  const float* bias = dir ? b1 : b0;
  u16* aux = dir ? aux1 : aux0;
  const int doflip = flip1 & dir;

  __shared__ __align__(16) u16 sA[128 * 32];
  __shared__ __align__(16) u16 sB[BN * 32];

  const int tid = threadIdx.x;
  const int lane = tid & 63, wave = tid >> 6;
  const int m0 = blockIdx.y * 128, n0 = blockIdx.x * BN;

  const f32x4 vzero = {0.f, 0.f, 0.f, 0.f};
  f32x4 acc[4][FJ];
#pragma unroll
  for (int i = 0; i < 4; ++i)
#pragma unroll
    for (int j = 0; j < FJ; ++j) acc[i][j] = vzero;

  const int lrow = lane & 15, kseg = lane >> 4;
  const int wm = (wave / NWC) * 64, wn = (wave % NWC) * WN;

  u32x4 va[2][2], vb[2][CB];

#define GLOAD(s, kt)                                                          \
  {                                                                           \
    _Pragma("unroll") for (int c = 0; c < 2; ++c) {                           \
      const int q = c * 256 + tid;                                            \
      int rA = m0 + (q >> 2);                                                 \
      if (doflip) rA ^= (L_SEQ - 1);                                          \
      va[s][c] = *(const u32x4*)(A + (size_t)rA * K + (kt) + (q & 3) * 8);    \
    }                                                                         \
    _Pragma("unroll") for (int c = 0; c < CB; ++c) {                          \
      const int q = c * 256 + tid;                                            \
      vb[s][c] = *(const u32x4*)(W + (size_t)(n0 + (q >> 2)) * K + (kt) +     \
                                 (q & 3) * 8);                                \
    }                                                                         \
  }
#define SSTORE(s)                                                             \
  {                                                                           \
    _Pragma("unroll") for (int c = 0; c < 2; ++c)                             \
        *(u32x4*)&sA[(c * 256 + tid) * 8] = va[s][c];                         \
    _Pragma("unroll") for (int c = 0; c < CB; ++c)                            \
        *(u32x4*)&sB[(c * 256 + tid) * 8] = vb[s][c];                         \
  }
#define COMPUTE()                                                             \
  {                                                                           \
    bf16x8 af[4], bfv[FJ];                                                    \
    _Pragma("unroll") for (int i = 0; i < 4; ++i)                             \
        af[i] = *(const bf16x8*)&sA[(wm + i * 16 + lrow) * 32 + kseg * 8];    \
    _Pragma("unroll") for (int j = 0; j < FJ; ++j)                            \
        bfv[j] = *(const bf16x8*)&sB[(wn + j * 16 + lrow) * 32 + kseg * 8];   \
    _Pragma("unroll") for (int i = 0; i < 4; ++i)                             \
        _Pragma("unroll") for (int j = 0; j < FJ; ++j)                        \
            acc[i][j] = __builtin_amdgcn_mfma_f32_16x16x32_bf16(              \
                af[i], bfv[j], acc[i][j], 0, 0, 0);                           \
  }

  GLOAD(0, 0)
  for (int kt = 0; kt < K; kt += 64) {
    __syncthreads();
    SSTORE(0)
    __syncthreads();
    GLOAD(1, kt + 32)
    COMPUTE()
    __syncthreads();
    SSTORE(1)
    __syncthreads();
    if (kt + 64 < K) GLOAD(0, kt + 64)
    COMPUTE()
  }
#undef GLOAD
#undef SSTORE
#undef COMPUTE

  // C/D layout: col = lane&15, row = (lane>>4)*4 + reg
  const int erow = (lane >> 4) * 4, ecol = lane & 15;
#pragma unroll
  for (int i = 0; i < 4; ++i) {
#pragma unroll
    for (int j = 0; j < FJ; ++j) {
#pragma unroll
      for (int r = 0; r < 4; ++r) {
        const int m = m0 + wm + i * 16 + erow + r;
        const int n = n0 + wn + j * 16 + ecol;
        float v = acc[i][j][r];
        if (MODE == 2) {
          const float xv = v + bias[n];
          v = fmaxf(xv, 0.f) + log1pf(__expf(-fabsf(xv)));
          aux[(size_t)m * N + n] = f2bf(v);
        } else if (MODE == 3) {
          aux[(size_t)m * N + n] = f2bf(v);
        } else {
          C[(size_t)m * N + n] = v;
          if (MODE == 1) {
            if (n < 64) aux[m * 64 + n] = f2bf(n < DTR ? v : 0.f);
          }
        }
      }
    }
  }
}

// ---------------- depthwise causal conv + SiLU (bf16 in/out) --------------
__launch_bounds__(256)
__global__ void k_conv(const u16* __restrict__ xz0, const u16* __restrict__ xz1,
                       u16* __restrict__ xc0, u16* __restrict__ xc1,
                       const float* __restrict__ w0, const float* __restrict__ w1,
                       const float* __restrict__ cb0, const float* __restrict__ cb1) {
  const int dir = blockIdx.z;
  const u16* xz = dir ? xz1 : xz0;
  u16* xc = dir ? xc1 : xc0;
  const float* w = dir ? w1 : w0;
  const float* cb = dir ? cb1 : cb0;
  const int d = blockIdx.x * 256 + threadIdx.x;
  const int tok = blockIdx.y;
  const int l = tok & (L_SEQ - 1);
  float s = cb[d];
#pragma unroll
  for (int j = 0; j < 4; ++j) {
    const int ls = l - 3 + j;
    if (ls >= 0) s += w[d * 4 + j] * bf2f(xz[(size_t)(tok - 3 + j) * (2 * DI) + d]);
  }
  const float r = s / (1.f + __expf(-s));
  xc[(size_t)tok * DI + d] = f2bf(r);
}

// ---------------- two-pass chunked scan -----------------------------------
// PASS 1: local scan from h=0 over TCH steps -> S[n], P[n]=prod(dA).
// PASS 2: scan from Hin, emit y=(sum_n h*C + xc*D)*silu(z) bf16.
// block = 64 thr (one wave, 64 d); grid (DI/64=24, NCH=32, 4=b*2+dir).
template <int PASS>
__launch_bounds__(64, 4)
__global__ void k_scan_pass(const u16* __restrict__ dl0, const u16* __restrict__ dl1,
                            const u16* __restrict__ xc0, const u16* __restrict__ xc1,
                            const float* __restrict__ dbc0, const float* __restrict__ dbc1,
                            const u16* __restrict__ xz0, const u16* __restrict__ xz1,
                            const float* __restrict__ al0, const float* __restrict__ al1,
                            const float* __restrict__ dp0, const float* __restrict__ dp1,
                            float* __restrict__ Sb, float* __restrict__ Pb,
                            const float* __restrict__ Hin,
                            u16* __restrict__ y0, u16* __restrict__ y1) {
  const int bdir = blockIdx.z;        // b*2 + dir
  const int dir = bdir & 1, b = bdir >> 1;
  const u16* delta = dir ? dl1 : dl0;
  const u16* xc = dir ? xc1 : xc0;
  const float* dbc = dir ? dbc1 : dbc0;
  const u16* xz = dir ? xz1 : xz0;
  const float* alog = dir ? al1 : al0;
  const float* dpp = dir ? dp1 : dp0;
  u16* y = dir ? y1 : y0;

  const int tid = threadIdx.x;
  const int d = blockIdx.x * 64 + tid;
  const int ch = blockIdx.y;
  const size_t tb = (size_t)b * L_SEQ;
  const int t0 = ch * TCH;

  __shared__ float sBC[TCH][32];      // B(16) | C(16) per step
#pragma unroll
  for (int p = 0; p < TCH * 32 / (64 * 4); ++p) {   // 4 iters
    const int idx = p * 64 + tid;
    const int rb = idx >> 3, cb = (idx & 7) * 4;
    *(f32x4*)&sBC[rb][cb] = *(const f32x4*)&dbc[(tb + t0 + rb) * 128 + 48 + cb];
  }

  float Af[16];
#pragma unroll
  for (int q = 0; q < 4; ++q) {
    const f32x4 a = *(const f32x4*)&alog[d * DS + q * 4];
#pragma unroll
    for (int j = 0; j < 4; ++j) Af[q * 4 + j] = -__expf(a[j]);
  }

  float h[16], Pp[16];
  if (PASS == 1) {
#pragma unroll
    for (int n = 0; n < 16; ++n) { h[n] = 0.f; Pp[n] = 1.f; }
  } else {
#pragma unroll
    for (int n = 0; n < 16; ++n)
      h[n] = Hin[(((size_t)bdir * NCH + ch) * 16 + n) * DI + d];
  }
  const float Dv = (PASS == 2) ? dpp[d] : 0.f;

  __syncthreads();

  u16 du[2][GP], xb[2][GP], zb[2][GP];
#define TLOAD(g, bu)                                                      \
  {                                                                       \
    _Pragma("unroll") for (int i = 0; i < GP; ++i) {                      \
      const size_t row = tb + t0 + (g) * GP + i;                          \
      du[bu][i] = delta[row * DI + d];                                    \
      xb[bu][i] = xc[row * DI + d];                                       \
      if (PASS == 2) zb[bu][i] = xz[row * (2 * DI) + DI + d];             \
    }                                                                     \
  }
  TLOAD(0, 0)
#pragma unroll 1
  for (int g = 0; g < TCH / GP; ++g) {
    const int bu = g & 1;
    if (g + 1 < TCH / GP) TLOAD(g + 1, bu ^ 1)
#pragma unroll
    for (int i = 0; i < GP; ++i) {
      const int t = g * GP + i;
      const float dlt = bf2f(du[bu][i]);
      const float xcv = bf2f(xb[bu][i]);
      const float dbx = dlt * xcv;
      float yv = 0.f;
#pragma unroll
      for (int q = 0; q < 4; ++q) {
        const f32x4 B4 = *(const f32x4*)&sBC[t][q * 4];
        f32x4 C4;
        if (PASS == 2) C4 = *(const f32x4*)&sBC[t][16 + q * 4];
#pragma unroll
        for (int j = 0; j < 4; ++j) {
          const int n = q * 4 + j;
          const float dA = __expf(dlt * Af[n]);
          if (PASS == 1) Pp[n] *= dA;
          h[n] = fmaf(dA, h[n], B4[j] * dbx);
          if (PASS == 2) yv = fmaf(h[n], C4[j], yv);
        }
      }
      if (PASS == 2) {
        const float zv = bf2f(zb[bu][i]);
        const float sz = zv / (1.f + __expf(-zv));
        y[(tb + t0 + t) * DI + d] = f2bf((yv + xcv * Dv) * sz);
      }
    }
  }
#undef TLOAD

  if (PASS == 1) {
#pragma unroll
    for (int n = 0; n < 16; ++n) {
      const size_t o = (((size_t)bdir * NCH + ch) * 16 + n) * DI + d;
      Sb[o] = h[n];
      Pb[o] = Pp[n];
    }
  }
}

// combine: sequential over NCH chunks per (bdir,n,d); writes Hin.
__launch_bounds__(256)
__global__ void k_comb(const float* __restrict__ Sb, const float* __restrict__ Pb,
                       float* __restrict__ Hin) {
  const int gid = blockIdx.x * 256 + threadIdx.x;  // 64*1536
  const int d = gid % DI;
  const int bn = gid / DI;            // bdir*16 + n
  const int bdir = bn >> 4, n = bn & 15;
  float H = 0.f;
#pragma unroll
  for (int c = 0; c < NCH; ++c) {
    const size_t o = (((size_t)bdir * NCH + c) * 16 + n) * DI + d;
    Hin[o] = H;
    H = fmaf(Pb[o], H, Sb[o]);
  }
}

// ---------------- final residual ------------------------------------------
__launch_bounds__(256)
__global__ void k_final(const float* __restrict__ x, const float* __restrict__ g0,
                        const float* __restrict__ g1, float* __restrict__ out) {
  const int c = blockIdx.x * 256 + threadIdx.x;
  const int tok = blockIdx.y;
  const int ftok = tok ^ (L_SEQ - 1);
  const size_t i = (size_t)tok * DM + c;
  out[i] = x[i] + g0[i] + g1[(size_t)ftok * DM + c];
}

extern "C" void kernel_launch(void* const* d_in, const int* in_sizes, int n_in,
                              void* d_out, int out_size, void* d_ws, size_t ws_size,
                              hipStream_t stream) {
  (void)n_in; (void)out_size; (void)in_sizes;
  const float* x      = (const float*)d_in[0];
  const float* ln_g   = (const float*)d_in[1];
  const float* ln_b   = (const float*)d_in[2];
  const float* in_w_f[2]  = {(const float*)d_in[3],  (const float*)d_in[12]};
  const float* conv_w[2]  = {(const float*)d_in[4],  (const float*)d_in[13]};
  const float* conv_b[2]  = {(const float*)d_in[5],  (const float*)d_in[14]};
  const float* xproj_w[2] = {(const float*)d_in[6],  (const float*)d_in[15]};
  const float* dt_w[2]    = {(const float*)d_in[7],  (const float*)d_in[16]};
  const float* dt_b[2]    = {(const float*)d_in[8],  (const float*)d_in[17]};
  const float* A_log[2]   = {(const float*)d_in[9],  (const float*)d_in[18]};
  const float* Dp[2]      = {(const float*)d_in[10], (const float*)d_in[19]};
  const float* out_w_f[2] = {(const float*)d_in[11], (const float*)d_in[20]};

  char* ws = (char*)d_ws;
  size_t off = 0;
  auto alloc = [&](size_t bytes) {
    void* p = ws + off;
    off = (off + bytes + 255) & ~(size_t)255;
    return p;
  };

  u16* inw[2];  for (int i = 0; i < 2; ++i) inw[i]  = (u16*)alloc((size_t)2 * DI * DM * 2);
  u16* outw[2]; for (int i = 0; i < 2; ++i) outw[i] = (u16*)alloc((size_t)DM * DI * 2);
  u16* x0 = (u16*)alloc((size_t)M_TOK * DM * 2);
  u16* xzb[2];    for (int i = 0; i < 2; ++i) xzb[i]  = (u16*)alloc((size_t)M_TOK * 2 * DI * 2);
  u16* xc[2];     for (int i = 0; i < 2; ++i) xc[i]   = (u16*)alloc((size_t)M_TOK * DI * 2);
  float* dbc[2];  for (int i = 0; i < 2; ++i) dbc[i]  = (float*)alloc((size_t)M_TOK * 128 * 4);
  u16* dtin[2];   for (int i = 0; i < 2; ++i) dtin[i] = (u16*)alloc((size_t)M_TOK * 64 * 2);
  u16* dltb[2];   for (int i = 0; i < 2; ++i) dltb[i] = (u16*)alloc((size_t)M_TOK * DI * 2);
  u16* yb[2];     for (int i = 0; i < 2; ++i) yb[i]   = (u16*)alloc((size_t)M_TOK * DI * 2);
  float* gout[2]; for (int i = 0; i < 2; ++i) gout[i] = (float*)alloc((size_t)M_TOK * DM * 4);
  u16* xpw[2];    for (int i = 0; i < 2; ++i) xpw[i]  = (u16*)alloc((size_t)128 * DI * 2);
  u16* dtwp[2];   for (int i = 0; i < 2; ++i) dtwp[i] = (u16*)alloc((size_t)DI * 64 * 2);
  float* Sb  = (float*)alloc((size_t)4 * NCH * 16 * DI * 4);
  float* Pb  = (float*)alloc((size_t)4 * NCH * 16 * DI * 4);
  float* Hin = (float*)alloc((size_t)4 * NCH * 16 * DI * 4);

  if (off > ws_size) return;  // sentinel: zero output -> absmax 4.97 diag

  // Make ws entry state identical on every call (first launch vs poisoned
  // timed launches) — removes any read-before-write divergence. ~30us.
  hipMemsetAsync(d_ws, 0, off, stream);

  for (int i = 0; i < 2; ++i) {
    k_cvt<<<dim3((2 * DI * DM + 255) / 256), dim3(256), 0, stream>>>(in_w_f[i], inw[i], 2 * DI * DM);
    k_cvt<<<dim3((DM * DI + 255) / 256), dim3(256), 0, stream>>>(out_w_f[i], outw[i], DM * DI);
  }

  k_ln<<<dim3(M_TOK), dim3(256), 0, stream>>>(x, ln_g, ln_b, x0);
  k_pad_xproj<<<dim3(6, 128, 2), dim3(256), 0, stream>>>(xproj_w[0], xproj_w[1], xpw[0], xpw[1]);
  k_pad_dtw<<<dim3(384, 2), dim3(256), 0, stream>>>(dt_w[0], dt_w[1], dtwp[0], dtwp[1]);
  // in-proj: xz = x0 @ in_w^T, bf16 out (MODE 3); dir1 reads row^1023
  k_gemm<128, 64, 3><<<dim3(24, 16, 2), dim3(256), 0, stream>>>(
      x0, x0, inw[0], inw[1], nullptr, nullptr, nullptr, nullptr, xzb[0], xzb[1],
      2 * DI, DM, 1);
  k_conv<<<dim3(6, M_TOK, 2), dim3(256), 0, stream>>>(
      xzb[0], xzb[1], xc[0], xc[1], conv_w[0], conv_w[1], conv_b[0], conv_b[1]);
  // x-proj: dbc = xc @ xproj^T (N padded 128) fp32 + bf16 dtin extraction
  k_gemm<128, 64, 1><<<dim3(1, 16, 2), dim3(256), 0, stream>>>(
      xc[0], xc[1], xpw[0], xpw[1], dbc[0], dbc[1], nullptr, nullptr, dtin[0], dtin[1],
      128, DI, 0);
  // dt-proj: delta = softplus(dtin @ dt_w^T + dt_b), bf16 out (MODE 2)
  k_gemm<128, 64, 2><<<dim3(12, 16, 2), dim3(256), 0, stream>>>(
      dtin[0], dtin[1], dtwp[0], dtwp[1], nullptr, nullptr, dt_b[0], dt_b[1], dltb[0], dltb[1],
      DI, 64, 0);
  // two-pass scan
  k_scan_pass<1><<<dim3(24, NCH, 4), dim3(64), 0, stream>>>(
      dltb[0], dltb[1], xc[0], xc[1], dbc[0], dbc[1], xzb[0], xzb[1],
      A_log[0], A_log[1], Dp[0], Dp[1], Sb, Pb, nullptr, nullptr, nullptr);
  k_comb<<<dim3(384), dim3(256), 0, stream>>>(Sb, Pb, Hin);
  k_scan_pass<2><<<dim3(24, NCH, 4), dim3(64), 0, stream>>>(
      dltb[0], dltb[1], xc[0], xc[1], dbc[0], dbc[1], xzb[0], xzb[1],
      A_log[0], A_log[1], Dp[0], Dp[1], Sb, Pb, Hin, yb[0], yb[1]);
  // out-proj: gout = y @ out_w^T  (BN=64 -> 384 blocks)
  k_gemm<64, 32, 0><<<dim3(12, 16, 2), dim3(256), 0, stream>>>(
      yb[0], yb[1], outw[0], outw[1], gout[0], gout[1], nullptr, nullptr, nullptr, nullptr,
      DM, DI, 0);
  k_final<<<dim3(3, M_TOK), dim3(256), 0, stream>>>(x, gout[0], gout[1], (float*)d_out);
}

// Round 13
// 443.176 us; speedup vs baseline: 1.1475x; 1.1475x over previous
//
#include <hip/hip_runtime.h>

// BiMambaBlock on gfx950. Inputs fp32 (bf16-valued), output fp32.
// Round 13 diff vs round 12: scan prefetch buffers back to FLOAT registers
// (bf16 converted at load). Round 9's all-u16 buffers with dynamic bu index
// were demoted to scratch -> 195 MB FETCH + 364 MB WRITE per pass, 2x slower.
// GP back to 4 (round-8-proven). TCH=32/NCH=32, memset, GEMMs unchanged.

typedef unsigned short u16;
typedef unsigned int u32;
typedef __bf16 bf16x8 __attribute__((ext_vector_type(8)));
typedef float f32x4 __attribute__((ext_vector_type(4)));
typedef u32 u32x4 __attribute__((ext_vector_type(4)));

#define L_SEQ 1024
#define DM 768
#define DI 1536
#define DS 16
#define DTR 48
#define M_TOK 2048
#define TCH 32
#define NCH (L_SEQ / TCH)  // 32
#define GP 4               // steps per load group in scan

__device__ __forceinline__ float bf2f(u16 u) {
  union { u32 i; float f; } v; v.i = ((u32)u) << 16; return v.f;
}
__device__ __forceinline__ u16 f2bf(float f) {
  union { float f; u32 i; } v; v.f = f;
  u32 r = v.i + 0x7fffu + ((v.i >> 16) & 1u);   // RNE
  return (u16)(r >> 16);
}

// ---------------- fp32 -> bf16 convert (GEMM weights) ----------------------
__launch_bounds__(256)
__global__ void k_cvt(const float* __restrict__ in, u16* __restrict__ out, int n) {
  const int i = blockIdx.x * 256 + threadIdx.x;
  if (i < n) out[i] = f2bf(in[i]);
}

// ---------------- LayerNorm ------------------------------------------------
__launch_bounds__(256)
__global__ void k_ln(const float* __restrict__ x, const float* __restrict__ g,
                     const float* __restrict__ b, u16* __restrict__ x0) {
  const int tok = blockIdx.x;
  const int tid = threadIdx.x;
  const float e0 = x[tok * DM + tid];
  const float e1 = x[tok * DM + tid + 256];
  const float e2 = x[tok * DM + tid + 512];
  float s = e0 + e1 + e2;
  float s2 = e0 * e0 + e1 * e1 + e2 * e2;
#pragma unroll
  for (int off = 1; off < 64; off <<= 1) {
    s += __shfl_xor(s, off, 64);
    s2 += __shfl_xor(s2, off, 64);
  }
  __shared__ float rs[4], rq[4];
  const int wave = tid >> 6, lane = tid & 63;
  if (lane == 0) { rs[wave] = s; rq[wave] = s2; }
  __syncthreads();
  s = rs[0] + rs[1] + rs[2] + rs[3];
  s2 = rq[0] + rq[1] + rq[2] + rq[3];
  const float mean = s * (1.0f / DM);
  const float var = s2 * (1.0f / DM) - mean * mean;
  const float inv = rsqrtf(var + 1e-5f);
  x0[tok * DM + tid]       = f2bf((e0 - mean) * inv * g[tid]       + b[tid]);
  x0[tok * DM + tid + 256] = f2bf((e1 - mean) * inv * g[tid + 256] + b[tid + 256]);
  x0[tok * DM + tid + 512] = f2bf((e2 - mean) * inv * g[tid + 512] + b[tid + 512]);
}

// ---------------- weight padding ------------------------------------------
__launch_bounds__(256)
__global__ void k_pad_xproj(const float* __restrict__ w0, const float* __restrict__ w1,
                            u16* __restrict__ o0, u16* __restrict__ o1) {
  const int dir = blockIdx.z;
  const float* w = dir ? w1 : w0;
  u16* o = dir ? o1 : o0;
  const int col = blockIdx.x * 256 + threadIdx.x;
  const int row = blockIdx.y;
  o[row * DI + col] = (row < 80) ? f2bf(w[row * DI + col]) : (u16)0;
}
__launch_bounds__(256)
__global__ void k_pad_dtw(const float* __restrict__ w0, const float* __restrict__ w1,
                          u16* __restrict__ o0, u16* __restrict__ o1) {
  const int dir = blockIdx.y;
  const float* w = dir ? w1 : w0;
  u16* o = dir ? o1 : o0;
  const int idx = blockIdx.x * 256 + threadIdx.x;
  const int row = idx >> 6, col = idx & 63;
  o[idx] = (col < DTR) ? f2bf(w[row * DTR + col]) : (u16)0;
}

// ---------------- GEMM: C[m,n] = sum_k A[m,k]*W[n,k], bf16 in -------------
// BM=128, BK=32, templated BN/WN. Register-prefetch pipeline, K % 64 == 0.
// MODE 0: fp32 C store.
// MODE 1: fp32 C store + bf16 aux[m*64+n] for n<64 (0 for n>=48).
// MODE 2: bf16 aux[m*N+n] = softplus(acc + bias[n]); no C store.
// MODE 3: bf16 aux[m*N+n] = acc; no C store.
template <int BN, int WN, int MODE>
__launch_bounds__(256)
__global__ void k_gemm(const u16* __restrict__ A0, const u16* __restrict__ A1,
                       const u16* __restrict__ W0, const u16* __restrict__ W1,
                       float* __restrict__ C0, float* __restrict__ C1,
                       const float* __restrict__ b0, const float* __restrict__ b1,
                       u16* __restrict__ aux0, u16* __restrict__ aux1,
                       int N, int K, int flip1) {
  constexpr int NWC = BN / WN;       // wave columns
  constexpr int FJ = WN / 16;        // n-frags per wave
  constexpr int CB = (BN * 32) / (256 * 8);  // B reg chunks per thread

  const int dir = blockIdx.z;
  const u16* A = dir ? A1 : A0;
  const u16* W = dir ? W1 : W0;
  float* C = dir ? C1 : C0;
  const float* bias = dir ? b1 : b0;
  u16* aux = dir ? aux1 : aux0;
  const int doflip = flip1 & dir;

  __shared__ __align__(16) u16 sA[128 * 32];
  __shared__ __align__(16) u16 sB[BN * 32];

  const int tid = threadIdx.x;
  const int lane = tid & 63, wave = tid >> 6;
  const int m0 = blockIdx.y * 128, n0 = blockIdx.x * BN;

  const f32x4 vzero = {0.f, 0.f, 0.f, 0.f};
  f32x4 acc[4][FJ];
#pragma unroll
  for (int i = 0; i < 4; ++i)
#pragma unroll
    for (int j = 0; j < FJ; ++j) acc[i][j] = vzero;

  const int lrow = lane & 15, kseg = lane >> 4;
  const int wm = (wave / NWC) * 64, wn = (wave % NWC) * WN;

  u32x4 va[2][2], vb[2][CB];

#define GLOAD(s, kt)                                                          \
  {                                                                           \
    _Pragma("unroll") for (int c = 0; c < 2; ++c) {                           \
      const int q = c * 256 + tid;                                            \
      int rA = m0 + (q >> 2);                                                 \
      if (doflip) rA ^= (L_SEQ - 1);                                          \
      va[s][c] = *(const u32x4*)(A + (size_t)rA * K + (kt) + (q & 3) * 8);    \
    }                                                                         \
    _Pragma("unroll") for (int c = 0; c < CB; ++c) {                          \
      const int q = c * 256 + tid;                                            \
      vb[s][c] = *(const u32x4*)(W + (size_t)(n0 + (q >> 2)) * K + (kt) +     \
                                 (q & 3) * 8);                                \
    }                                                                         \
  }
#define SSTORE(s)                                                             \
  {                                                                           \
    _Pragma("unroll") for (int c = 0; c < 2; ++c)                             \
        *(u32x4*)&sA[(c * 256 + tid) * 8] = va[s][c];                         \
    _Pragma("unroll") for (int c = 0; c < CB; ++c)                            \
        *(u32x4*)&sB[(c * 256 + tid) * 8] = vb[s][c];                         \
  }
#define COMPUTE()                                                             \
  {                                                                           \
    bf16x8 af[4], bfv[FJ];                                                    \
    _Pragma("unroll") for (int i = 0; i < 4; ++i)                             \
        af[i] = *(const bf16x8*)&sA[(wm + i * 16 + lrow) * 32 + kseg * 8];    \
    _Pragma("unroll") for (int j = 0; j < FJ; ++j)                            \
        bfv[j] = *(const bf16x8*)&sB[(wn + j * 16 + lrow) * 32 + kseg * 8];   \
    _Pragma("unroll") for (int i = 0; i < 4; ++i)                             \
        _Pragma("unroll") for (int j = 0; j < FJ; ++j)                        \
            acc[i][j] = __builtin_amdgcn_mfma_f32_16x16x32_bf16(              \
                af[i], bfv[j], acc[i][j], 0, 0, 0);                           \
  }

  GLOAD(0, 0)
  for (int kt = 0; kt < K; kt += 64) {
    __syncthreads();
    SSTORE(0)
    __syncthreads();
    GLOAD(1, kt + 32)
    COMPUTE()
    __syncthreads();
    SSTORE(1)
    __syncthreads();
    if (kt + 64 < K) GLOAD(0, kt + 64)
    COMPUTE()
  }
#undef GLOAD
#undef SSTORE
#undef COMPUTE

  // C/D layout: col = lane&15, row = (lane>>4)*4 + reg
  const int erow = (lane >> 4) * 4, ecol = lane & 15;
#pragma unroll
  for (int i = 0; i < 4; ++i) {
#pragma unroll
    for (int j = 0; j < FJ; ++j) {
#pragma unroll
      for (int r = 0; r < 4; ++r) {
        const int m = m0 + wm + i * 16 + erow + r;
        const int n = n0 + wn + j * 16 + ecol;
        float v = acc[i][j][r];
        if (MODE == 2) {
          const float xv = v + bias[n];
          v = fmaxf(xv, 0.f) + log1pf(__expf(-fabsf(xv)));
          aux[(size_t)m * N + n] = f2bf(v);
        } else if (MODE == 3) {
          aux[(size_t)m * N + n] = f2bf(v);
        } else {
          C[(size_t)m * N + n] = v;
          if (MODE == 1) {
            if (n < 64) aux[m * 64 + n] = f2bf(n < DTR ? v : 0.f);
          }
        }
      }
    }
  }
}

// ---------------- depthwise causal conv + SiLU (bf16 in/out) --------------
__launch_bounds__(256)
__global__ void k_conv(const u16* __restrict__ xz0, const u16* __restrict__ xz1,
                       u16* __restrict__ xc0, u16* __restrict__ xc1,
                       const float* __restrict__ w0, const float* __restrict__ w1,
                       const float* __restrict__ cb0, const float* __restrict__ cb1) {
  const int dir = blockIdx.z;
  const u16* xz = dir ? xz1 : xz0;
  u16* xc = dir ? xc1 : xc0;
  const float* w = dir ? w1 : w0;
  const float* cb = dir ? cb1 : cb0;
  const int d = blockIdx.x * 256 + threadIdx.x;
  const int tok = blockIdx.y;
  const int l = tok & (L_SEQ - 1);
  float s = cb[d];
#pragma unroll
  for (int j = 0; j < 4; ++j) {
    const int ls = l - 3 + j;
    if (ls >= 0) s += w[d * 4 + j] * bf2f(xz[(size_t)(tok - 3 + j) * (2 * DI) + d]);
  }
  const float r = s / (1.f + __expf(-s));
  xc[(size_t)tok * DI + d] = f2bf(r);
}

// ---------------- two-pass chunked scan -----------------------------------
// PASS 1: local scan from h=0 over TCH steps -> S[n], P[n]=prod(dA).
// PASS 2: scan from Hin, emit y=(sum_n h*C + xc*D)*silu(z) bf16.
// block = 64 thr (one wave, 64 d); grid (DI/64=24, NCH=32, 4=b*2+dir).
// Prefetch buffers are FLOAT regs (bf16 converted at load) — u16 arrays get
// scratch-demoted (round 12: 195+364 MB scratch traffic per pass).
template <int PASS>
__launch_bounds__(64, 4)
__global__ void k_scan_pass(const u16* __restrict__ dl0, const u16* __restrict__ dl1,
                            const u16* __restrict__ xc0, const u16* __restrict__ xc1,
                            const float* __restrict__ dbc0, const float* __restrict__ dbc1,
                            const u16* __restrict__ xz0, const u16* __restrict__ xz1,
                            const float* __restrict__ al0, const float* __restrict__ al1,
                            const float* __restrict__ dp0, const float* __restrict__ dp1,
                            float* __restrict__ Sb, float* __restrict__ Pb,
                            const float* __restrict__ Hin,
                            u16* __restrict__ y0, u16* __restrict__ y1) {
  const int bdir = blockIdx.z;        // b*2 + dir
  const int dir = bdir & 1, b = bdir >> 1;
  const u16* delta = dir ? dl1 : dl0;
  const u16* xc = dir ? xc1 : xc0;
  const float* dbc = dir ? dbc1 : dbc0;
  const u16* xz = dir ? xz1 : xz0;
  const float* alog = dir ? al1 : al0;
  const float* dpp = dir ? dp1 : dp0;
  u16* y = dir ? y1 : y0;

  const int tid = threadIdx.x;
  const int d = blockIdx.x * 64 + tid;
  const int ch = blockIdx.y;
  const size_t tb = (size_t)b * L_SEQ;
  const int t0 = ch * TCH;

  __shared__ float sBC[TCH][32];      // B(16) | C(16) per step
#pragma unroll
  for (int p = 0; p < TCH * 32 / (64 * 4); ++p) {   // 4 iters
    const int idx = p * 64 + tid;
    const int rb = idx >> 3, cb = (idx & 7) * 4;
    *(f32x4*)&sBC[rb][cb] = *(const f32x4*)&dbc[(tb + t0 + rb) * 128 + 48 + cb];
  }

  float Af[16];
#pragma unroll
  for (int q = 0; q < 4; ++q) {
    const f32x4 a = *(const f32x4*)&alog[d * DS + q * 4];
#pragma unroll
    for (int j = 0; j < 4; ++j) Af[q * 4 + j] = -__expf(a[j]);
  }

  float h[16], Pp[16];
  if (PASS == 1) {
#pragma unroll
    for (int n = 0; n < 16; ++n) { h[n] = 0.f; Pp[n] = 1.f; }
  } else {
#pragma unroll
    for (int n = 0; n < 16; ++n)
      h[n] = Hin[(((size_t)bdir * NCH + ch) * 16 + n) * DI + d];
  }
  const float Dv = (PASS == 2) ? dpp[d] : 0.f;

  __syncthreads();

  float db[2][GP], xb[2][GP], zb[2][GP];
#define TLOAD(g, bu)                                                      \
  {                                                                       \
    _Pragma("unroll") for (int i = 0; i < GP; ++i) {                      \
      const size_t row = tb + t0 + (g) * GP + i;                          \
      db[bu][i] = bf2f(delta[row * DI + d]);                              \
      xb[bu][i] = bf2f(xc[row * DI + d]);                                 \
      if (PASS == 2) zb[bu][i] = bf2f(xz[row * (2 * DI) + DI + d]);       \
    }                                                                     \
  }
  TLOAD(0, 0)
#pragma unroll 1
  for (int g = 0; g < TCH / GP; ++g) {
    const int bu = g & 1;
    if (g + 1 < TCH / GP) TLOAD(g + 1, bu ^ 1)
#pragma unroll
    for (int i = 0; i < GP; ++i) {
      const int t = g * GP + i;
      const float dlt = db[bu][i];
      const float xcv = xb[bu][i];
      const float dbx = dlt * xcv;
      float yv = 0.f;
#pragma unroll
      for (int q = 0; q < 4; ++q) {
        const f32x4 B4 = *(const f32x4*)&sBC[t][q * 4];
        f32x4 C4;
        if (PASS == 2) C4 = *(const f32x4*)&sBC[t][16 + q * 4];
#pragma unroll
        for (int j = 0; j < 4; ++j) {
          const int n = q * 4 + j;
          const float dA = __expf(dlt * Af[n]);
          if (PASS == 1) Pp[n] *= dA;
          h[n] = fmaf(dA, h[n], B4[j] * dbx);
          if (PASS == 2) yv = fmaf(h[n], C4[j], yv);
        }
      }
      if (PASS == 2) {
        const float zv = zb[bu][i];
        const float sz = zv / (1.f + __expf(-zv));
        y[(tb + t0 + t) * DI + d] = f2bf((yv + xcv * Dv) * sz);
      }
    }
  }
#undef TLOAD

  if (PASS == 1) {
#pragma unroll
    for (int n = 0; n < 16; ++n) {
      const size_t o = (((size_t)bdir * NCH + ch) * 16 + n) * DI + d;
      Sb[o] = h[n];
      Pb[o] = Pp[n];
    }
  }
}

// combine: sequential over NCH chunks per (bdir,n,d); writes Hin.
__launch_bounds__(256)
__global__ void k_comb(const float* __restrict__ Sb, const float* __restrict__ Pb,
                       float* __restrict__ Hin) {
  const int gid = blockIdx.x * 256 + threadIdx.x;  // 64*1536
  const int d = gid % DI;
  const int bn = gid / DI;            // bdir*16 + n
  const int bdir = bn >> 4, n = bn & 15;
  float H = 0.f;
#pragma unroll
  for (int c = 0; c < NCH; ++c) {
    const size_t o = (((size_t)bdir * NCH + c) * 16 + n) * DI + d;
    Hin[o] = H;
    H = fmaf(Pb[o], H, Sb[o]);
  }
}

// ---------------- final residual ------------------------------------------
__launch_bounds__(256)
__global__ void k_final(const float* __restrict__ x, const float* __restrict__ g0,
                        const float* __restrict__ g1, float* __restrict__ out) {
  const int c = blockIdx.x * 256 + threadIdx.x;
  const int tok = blockIdx.y;
  const int ftok = tok ^ (L_SEQ - 1);
  const size_t i = (size_t)tok * DM + c;
  out[i] = x[i] + g0[i] + g1[(size_t)ftok * DM + c];
}

extern "C" void kernel_launch(void* const* d_in, const int* in_sizes, int n_in,
                              void* d_out, int out_size, void* d_ws, size_t ws_size,
                              hipStream_t stream) {
  (void)n_in; (void)out_size; (void)in_sizes;
  const float* x      = (const float*)d_in[0];
  const float* ln_g   = (const float*)d_in[1];
  const float* ln_b   = (const float*)d_in[2];
  const float* in_w_f[2]  = {(const float*)d_in[3],  (const float*)d_in[12]};
  const float* conv_w[2]  = {(const float*)d_in[4],  (const float*)d_in[13]};
  const float* conv_b[2]  = {(const float*)d_in[5],  (const float*)d_in[14]};
  const float* xproj_w[2] = {(const float*)d_in[6],  (const float*)d_in[15]};
  const float* dt_w[2]    = {(const float*)d_in[7],  (const float*)d_in[16]};
  const float* dt_b[2]    = {(const float*)d_in[8],  (const float*)d_in[17]};
  const float* A_log[2]   = {(const float*)d_in[9],  (const float*)d_in[18]};
  const float* Dp[2]      = {(const float*)d_in[10], (const float*)d_in[19]};
  const float* out_w_f[2] = {(const float*)d_in[11], (const float*)d_in[20]};

  char* ws = (char*)d_ws;
  size_t off = 0;
  auto alloc = [&](size_t bytes) {
    void* p = ws + off;
    off = (off + bytes + 255) & ~(size_t)255;
    return p;
  };

  u16* inw[2];  for (int i = 0; i < 2; ++i) inw[i]  = (u16*)alloc((size_t)2 * DI * DM * 2);
  u16* outw[2]; for (int i = 0; i < 2; ++i) outw[i] = (u16*)alloc((size_t)DM * DI * 2);
  u16* x0 = (u16*)alloc((size_t)M_TOK * DM * 2);
  u16* xzb[2];    for (int i = 0; i < 2; ++i) xzb[i]  = (u16*)alloc((size_t)M_TOK * 2 * DI * 2);
  u16* xc[2];     for (int i = 0; i < 2; ++i) xc[i]   = (u16*)alloc((size_t)M_TOK * DI * 2);
  float* dbc[2];  for (int i = 0; i < 2; ++i) dbc[i]  = (float*)alloc((size_t)M_TOK * 128 * 4);
  u16* dtin[2];   for (int i = 0; i < 2; ++i) dtin[i] = (u16*)alloc((size_t)M_TOK * 64 * 2);
  u16* dltb[2];   for (int i = 0; i < 2; ++i) dltb[i] = (u16*)alloc((size_t)M_TOK * DI * 2);
  u16* yb[2];     for (int i = 0; i < 2; ++i) yb[i]   = (u16*)alloc((size_t)M_TOK * DI * 2);
  float* gout[2]; for (int i = 0; i < 2; ++i) gout[i] = (float*)alloc((size_t)M_TOK * DM * 4);
  u16* xpw[2];    for (int i = 0; i < 2; ++i) xpw[i]  = (u16*)alloc((size_t)128 * DI * 2);
  u16* dtwp[2];   for (int i = 0; i < 2; ++i) dtwp[i] = (u16*)alloc((size_t)DI * 64 * 2);
  float* Sb  = (float*)alloc((size_t)4 * NCH * 16 * DI * 4);
  float* Pb  = (float*)alloc((size_t)4 * NCH * 16 * DI * 4);
  float* Hin = (float*)alloc((size_t)4 * NCH * 16 * DI * 4);

  if (off > ws_size) return;  // sentinel: zero output -> absmax 4.97 diag

  // ws entry state must be identical on every call (empirically required —
  // round 11 diverged post-timing without this).
  hipMemsetAsync(d_ws, 0, off, stream);

  for (int i = 0; i < 2; ++i) {
    k_cvt<<<dim3((2 * DI * DM + 255) / 256), dim3(256), 0, stream>>>(in_w_f[i], inw[i], 2 * DI * DM);
    k_cvt<<<dim3((DM * DI + 255) / 256), dim3(256), 0, stream>>>(out_w_f[i], outw[i], DM * DI);
  }

  k_ln<<<dim3(M_TOK), dim3(256), 0, stream>>>(x, ln_g, ln_b, x0);
  k_pad_xproj<<<dim3(6, 128, 2), dim3(256), 0, stream>>>(xproj_w[0], xproj_w[1], xpw[0], xpw[1]);
  k_pad_dtw<<<dim3(384, 2), dim3(256), 0, stream>>>(dt_w[0], dt_w[1], dtwp[0], dtwp[1]);
  // in-proj: xz = x0 @ in_w^T, bf16 out (MODE 3); dir1 reads row^1023
  k_gemm<128, 64, 3><<<dim3(24, 16, 2), dim3(256), 0, stream>>>(
      x0, x0, inw[0], inw[1], nullptr, nullptr, nullptr, nullptr, xzb[0], xzb[1],
      2 * DI, DM, 1);
  k_conv<<<dim3(6, M_TOK, 2), dim3(256), 0, stream>>>(
      xzb[0], xzb[1], xc[0], xc[1], conv_w[0], conv_w[1], conv_b[0], conv_b[1]);
  // x-proj: dbc = xc @ xproj^T (N padded 128) fp32 + bf16 dtin extraction
  k_gemm<128, 64, 1><<<dim3(1, 16, 2), dim3(256), 0, stream>>>(
      xc[0], xc[1], xpw[0], xpw[1], dbc[0], dbc[1], nullptr, nullptr, dtin[0], dtin[1],
      128, DI, 0);
  // dt-proj: delta = softplus(dtin @ dt_w^T + dt_b), bf16 out (MODE 2)
  k_gemm<128, 64, 2><<<dim3(12, 16, 2), dim3(256), 0, stream>>>(
      dtin[0], dtin[1], dtwp[0], dtwp[1], nullptr, nullptr, dt_b[0], dt_b[1], dltb[0], dltb[1],
      DI, 64, 0);
  // two-pass scan
  k_scan_pass<1><<<dim3(24, NCH, 4), dim3(64), 0, stream>>>(
      dltb[0], dltb[1], xc[0], xc[1], dbc[0], dbc[1], xzb[0], xzb[1],
      A_log[0], A_log[1], Dp[0], Dp[1], Sb, Pb, nullptr, nullptr, nullptr);
  k_comb<<<dim3(384), dim3(256), 0, stream>>>(Sb, Pb, Hin);
  k_scan_pass<2><<<dim3(24, NCH, 4), dim3(64), 0, stream>>>(
      dltb[0], dltb[1], xc[0], xc[1], dbc[0], dbc[1], xzb[0], xzb[1],
      A_log[0], A_log[1], Dp[0], Dp[1], Sb, Pb, Hin, yb[0], yb[1]);
  // out-proj: gout = y @ out_w^T  (BN=64 -> 384 blocks)
  k_gemm<64, 32, 0><<<dim3(12, 16, 2), dim3(256), 0, stream>>>(
      yb[0], yb[1], outw[0], outw[1], gout[0], gout[1], nullptr, nullptr, nullptr, nullptr,
      DM, DI, 0);
  k_final<<<dim3(3, M_TOK), dim3(256), 0, stream>>>(x, gout[0], gout[1], (float*)d_out);
}

// Round 14
// 394.454 us; speedup vs baseline: 1.2893x; 1.1235x over previous
//
#include <hip/hip_runtime.h>

// BiMambaBlock on gfx950. Inputs fp32 (bf16-valued), output fp32.
// Round 14 diff vs round 13: GEMMs retiled for latency depth.
//  - generalized k_gemm<BM,BN,WROWS,WCOLS,MODE,NS>; BM=64 tiles double block
//    count (in-proj 1536 blocks = 6/CU, was 3/CU).
//  - split-K with deterministic partial slabs (MODE 4) + reduce: x-proj NS=8
//    (512 blocks x 6 round-trips; was 32 blocks x 48!), out-proj NS=2.
//  - k_xred: sums x-proj partials -> dbc fp32 + dtin bf16. k_final sums
//    out-proj partials. Partials alias Sb/Pb (dead outside scan window).
// Scan/conv/ln/memset unchanged from round 13.

typedef unsigned short u16;
typedef unsigned int u32;
typedef __bf16 bf16x8 __attribute__((ext_vector_type(8)));
typedef float f32x4 __attribute__((ext_vector_type(4)));
typedef u32 u32x4 __attribute__((ext_vector_type(4)));

#define L_SEQ 1024
#define DM 768
#define DI 1536
#define DS 16
#define DTR 48
#define M_TOK 2048
#define TCH 32
#define NCH (L_SEQ / TCH)  // 32
#define GP 4               // steps per load group in scan

__device__ __forceinline__ float bf2f(u16 u) {
  union { u32 i; float f; } v; v.i = ((u32)u) << 16; return v.f;
}
__device__ __forceinline__ u16 f2bf(float f) {
  union { float f; u32 i; } v; v.f = f;
  u32 r = v.i + 0x7fffu + ((v.i >> 16) & 1u);   // RNE
  return (u16)(r >> 16);
}

// ---------------- fp32 -> bf16 convert (GEMM weights) ----------------------
__launch_bounds__(256)
__global__ void k_cvt(const float* __restrict__ in, u16* __restrict__ out, int n) {
  const int i = blockIdx.x * 256 + threadIdx.x;
  if (i < n) out[i] = f2bf(in[i]);
}

// ---------------- LayerNorm ------------------------------------------------
__launch_bounds__(256)
__global__ void k_ln(const float* __restrict__ x, const float* __restrict__ g,
                     const float* __restrict__ b, u16* __restrict__ x0) {
  const int tok = blockIdx.x;
  const int tid = threadIdx.x;
  const float e0 = x[tok * DM + tid];
  const float e1 = x[tok * DM + tid + 256];
  const float e2 = x[tok * DM + tid + 512];
  float s = e0 + e1 + e2;
  float s2 = e0 * e0 + e1 * e1 + e2 * e2;
#pragma unroll
  for (int off = 1; off < 64; off <<= 1) {
    s += __shfl_xor(s, off, 64);
    s2 += __shfl_xor(s2, off, 64);
  }
  __shared__ float rs[4], rq[4];
  const int wave = tid >> 6, lane = tid & 63;
  if (lane == 0) { rs[wave] = s; rq[wave] = s2; }
  __syncthreads();
  s = rs[0] + rs[1] + rs[2] + rs[3];
  s2 = rq[0] + rq[1] + rq[2] + rq[3];
  const float mean = s * (1.0f / DM);
  const float var = s2 * (1.0f / DM) - mean * mean;
  const float inv = rsqrtf(var + 1e-5f);
  x0[tok * DM + tid]       = f2bf((e0 - mean) * inv * g[tid]       + b[tid]);
  x0[tok * DM + tid + 256] = f2bf((e1 - mean) * inv * g[tid + 256] + b[tid + 256]);
  x0[tok * DM + tid + 512] = f2bf((e2 - mean) * inv * g[tid + 512] + b[tid + 512]);
}

// ---------------- weight padding ------------------------------------------
__launch_bounds__(256)
__global__ void k_pad_xproj(const float* __restrict__ w0, const float* __restrict__ w1,
                            u16* __restrict__ o0, u16* __restrict__ o1) {
  const int dir = blockIdx.z;
  const float* w = dir ? w1 : w0;
  u16* o = dir ? o1 : o0;
  const int col = blockIdx.x * 256 + threadIdx.x;
  const int row = blockIdx.y;
  o[row * DI + col] = (row < 80) ? f2bf(w[row * DI + col]) : (u16)0;
}
__launch_bounds__(256)
__global__ void k_pad_dtw(const float* __restrict__ w0, const float* __restrict__ w1,
                          u16* __restrict__ o0, u16* __restrict__ o1) {
  const int dir = blockIdx.y;
  const float* w = dir ? w1 : w0;
  u16* o = dir ? o1 : o0;
  const int idx = blockIdx.x * 256 + threadIdx.x;
  const int row = idx >> 6, col = idx & 63;
  o[idx] = (col < DTR) ? f2bf(w[row * DTR + col]) : (u16)0;
}

// ---------------- GEMM: C[m,n] = sum_k A[m,k]*W[n,k], bf16 in -------------
// Tiles: BM x BN, BK=32, 256 thr = 4 waves arranged WROWS x WCOLS.
// Register-prefetch pipeline; K_eff = K/NS must be a multiple of 64.
// blockIdx.z = dir*NS + ks (split-K slab index).
// MODE 2: bf16 aux[m*N+n] = softplus(acc + bias[n]).
// MODE 3: bf16 aux[m*N+n] = acc.
// MODE 4: fp32 C[ks*M_TOK*N + m*N + n] = acc  (deterministic split-K slab).
template <int BM, int BN, int WROWS, int WCOLS, int MODE, int NS>
__launch_bounds__(256)
__global__ void k_gemm(const u16* __restrict__ A0, const u16* __restrict__ A1,
                       const u16* __restrict__ W0, const u16* __restrict__ W1,
                       float* __restrict__ C0, float* __restrict__ C1,
                       const float* __restrict__ b0, const float* __restrict__ b1,
                       u16* __restrict__ aux0, u16* __restrict__ aux1,
                       int N, int K, int flip1) {
  constexpr int WTM = BM / WROWS;   // wave m-tile
  constexpr int WTN = BN / WCOLS;   // wave n-tile
  constexpr int FI = WTM / 16;
  constexpr int FJ = WTN / 16;
  constexpr int CA = (BM * 32) / (256 * 8);  // A 16B chunks per thread
  constexpr int CB = (BN * 32) / (256 * 8);  // B 16B chunks per thread

  const int zz = blockIdx.z;
  const int dir = zz / NS, ks = zz % NS;
  const u16* A = dir ? A1 : A0;
  const u16* W = dir ? W1 : W0;
  float* C = dir ? C1 : C0;
  const float* bias = dir ? b1 : b0;
  u16* aux = dir ? aux1 : aux0;
  const int doflip = flip1 & dir;
  const int Keff = K / NS;
  const int kbase = ks * Keff;

  __shared__ __align__(16) u16 sA[BM * 32];
  __shared__ __align__(16) u16 sB[BN * 32];

  const int tid = threadIdx.x;
  const int lane = tid & 63, wave = tid >> 6;
  const int m0 = blockIdx.y * BM, n0 = blockIdx.x * BN;

  const f32x4 vzero = {0.f, 0.f, 0.f, 0.f};
  f32x4 acc[FI][FJ];
#pragma unroll
  for (int i = 0; i < FI; ++i)
#pragma unroll
    for (int j = 0; j < FJ; ++j) acc[i][j] = vzero;

  const int lrow = lane & 15, kseg = lane >> 4;
  const int wm = (wave / WCOLS) * WTM, wn = (wave % WCOLS) * WTN;

  u32x4 va[2][CA], vb[2][CB];

#define GLOAD(s, kt)                                                          \
  {                                                                           \
    _Pragma("unroll") for (int c = 0; c < CA; ++c) {                          \
      const int q = c * 256 + tid;                                            \
      int rA = m0 + (q >> 2);                                                 \
      if (doflip) rA ^= (L_SEQ - 1);                                          \
      va[s][c] = *(const u32x4*)(A + (size_t)rA * K + (kt) + (q & 3) * 8);    \
    }                                                                         \
    _Pragma("unroll") for (int c = 0; c < CB; ++c) {                          \
      const int q = c * 256 + tid;                                            \
      vb[s][c] = *(const u32x4*)(W + (size_t)(n0 + (q >> 2)) * K + (kt) +     \
                                 (q & 3) * 8);                                \
    }                                                                         \
  }
#define SSTORE(s)                                                             \
  {                                                                           \
    _Pragma("unroll") for (int c = 0; c < CA; ++c)                            \
        *(u32x4*)&sA[(c * 256 + tid) * 8] = va[s][c];                         \
    _Pragma("unroll") for (int c = 0; c < CB; ++c)                            \
        *(u32x4*)&sB[(c * 256 + tid) * 8] = vb[s][c];                         \
  }
#define COMPUTE()                                                             \
  {                                                                           \
    bf16x8 af[FI], bfv[FJ];                                                   \
    _Pragma("unroll") for (int i = 0; i < FI; ++i)                            \
        af[i] = *(const bf16x8*)&sA[(wm + i * 16 + lrow) * 32 + kseg * 8];    \
    _Pragma("unroll") for (int j = 0; j < FJ; ++j)                            \
        bfv[j] = *(const bf16x8*)&sB[(wn + j * 16 + lrow) * 32 + kseg * 8];   \
    _Pragma("unroll") for (int i = 0; i < FI; ++i)                            \
        _Pragma("unroll") for (int j = 0; j < FJ; ++j)                        \
            acc[i][j] = __builtin_amdgcn_mfma_f32_16x16x32_bf16(              \
                af[i], bfv[j], acc[i][j], 0, 0, 0);                           \
  }

  GLOAD(0, kbase)
  for (int kt = 0; kt < Keff; kt += 64) {
    __syncthreads();
    SSTORE(0)
    __syncthreads();
    GLOAD(1, kbase + kt + 32)
    COMPUTE()
    __syncthreads();
    SSTORE(1)
    __syncthreads();
    if (kt + 64 < Keff) GLOAD(0, kbase + kt + 64)
    COMPUTE()
  }
#undef GLOAD
#undef SSTORE
#undef COMPUTE

  // C/D layout: col = lane&15, row = (lane>>4)*4 + reg
  const int erow = (lane >> 4) * 4, ecol = lane & 15;
#pragma unroll
  for (int i = 0; i < FI; ++i) {
#pragma unroll
    for (int j = 0; j < FJ; ++j) {
#pragma unroll
      for (int r = 0; r < 4; ++r) {
        const int m = m0 + wm + i * 16 + erow + r;
        const int n = n0 + wn + j * 16 + ecol;
        float v = acc[i][j][r];
        if (MODE == 2) {
          const float xv = v + bias[n];
          v = fmaxf(xv, 0.f) + log1pf(__expf(-fabsf(xv)));
          aux[(size_t)m * N + n] = f2bf(v);
        } else if (MODE == 3) {
          aux[(size_t)m * N + n] = f2bf(v);
        } else {  // MODE 4: split-K partial slab
          C[(size_t)ks * M_TOK * N + (size_t)m * N + n] = v;
        }
      }
    }
  }
}

// ---------------- x-proj partial reduce -> dbc fp32 + dtin bf16 -----------
// xpp layout per dir: 8 slabs of [M_TOK x 128]. grid (1024, 2).
__launch_bounds__(256)
__global__ void k_xred(const float* __restrict__ xpp, float* __restrict__ dbc0,
                       float* __restrict__ dbc1, u16* __restrict__ dt0,
                       u16* __restrict__ dt1) {
  const int dir = blockIdx.y;
  const float* p = xpp + (size_t)dir * 8 * M_TOK * 128;
  float* dbc = dir ? dbc1 : dbc0;
  u16* dtin = dir ? dt1 : dt0;
  const int idx = blockIdx.x * 256 + threadIdx.x;  // m*128+col
  float v = 0.f;
#pragma unroll
  for (int s = 0; s < 8; ++s) v += p[(size_t)s * M_TOK * 128 + idx];
  dbc[idx] = v;
  const int col = idx & 127;
  if (col < 64) {
    const int m = idx >> 7;
    dtin[m * 64 + col] = f2bf(col < DTR ? v : 0.f);
  }
}

// ---------------- depthwise causal conv + SiLU (bf16 in/out) --------------
__launch_bounds__(256)
__global__ void k_conv(const u16* __restrict__ xz0, const u16* __restrict__ xz1,
                       u16* __restrict__ xc0, u16* __restrict__ xc1,
                       const float* __restrict__ w0, const float* __restrict__ w1,
                       const float* __restrict__ cb0, const float* __restrict__ cb1) {
  const int dir = blockIdx.z;
  const u16* xz = dir ? xz1 : xz0;
  u16* xc = dir ? xc1 : xc0;
  const float* w = dir ? w1 : w0;
  const float* cb = dir ? cb1 : cb0;
  const int d = blockIdx.x * 256 + threadIdx.x;
  const int tok = blockIdx.y;
  const int l = tok & (L_SEQ - 1);
  float s = cb[d];
#pragma unroll
  for (int j = 0; j < 4; ++j) {
    const int ls = l - 3 + j;
    if (ls >= 0) s += w[d * 4 + j] * bf2f(xz[(size_t)(tok - 3 + j) * (2 * DI) + d]);
  }
  const float r = s / (1.f + __expf(-s));
  xc[(size_t)tok * DI + d] = f2bf(r);
}

// ---------------- two-pass chunked scan (unchanged from round 13) ---------
template <int PASS>
__launch_bounds__(64, 4)
__global__ void k_scan_pass(const u16* __restrict__ dl0, const u16* __restrict__ dl1,
                            const u16* __restrict__ xc0, const u16* __restrict__ xc1,
                            const float* __restrict__ dbc0, const float* __restrict__ dbc1,
                            const u16* __restrict__ xz0, const u16* __restrict__ xz1,
                            const float* __restrict__ al0, const float* __restrict__ al1,
                            const float* __restrict__ dp0, const float* __restrict__ dp1,
                            float* __restrict__ Sb, float* __restrict__ Pb,
                            const float* __restrict__ Hin,
                            u16* __restrict__ y0, u16* __restrict__ y1) {
  const int bdir = blockIdx.z;        // b*2 + dir
  const int dir = bdir & 1, b = bdir >> 1;
  const u16* delta = dir ? dl1 : dl0;
  const u16* xc = dir ? xc1 : xc0;
  const float* dbc = dir ? dbc1 : dbc0;
  const u16* xz = dir ? xz1 : xz0;
  const float* alog = dir ? al1 : al0;
  const float* dpp = dir ? dp1 : dp0;
  u16* y = dir ? y1 : y0;

  const int tid = threadIdx.x;
  const int d = blockIdx.x * 64 + tid;
  const int ch = blockIdx.y;
  const size_t tb = (size_t)b * L_SEQ;
  const int t0 = ch * TCH;

  __shared__ float sBC[TCH][32];      // B(16) | C(16) per step
#pragma unroll
  for (int p = 0; p < TCH * 32 / (64 * 4); ++p) {
    const int idx = p * 64 + tid;
    const int rb = idx >> 3, cb = (idx & 7) * 4;
    *(f32x4*)&sBC[rb][cb] = *(const f32x4*)&dbc[(tb + t0 + rb) * 128 + 48 + cb];
  }

  float Af[16];
#pragma unroll
  for (int q = 0; q < 4; ++q) {
    const f32x4 a = *(const f32x4*)&alog[d * DS + q * 4];
#pragma unroll
    for (int j = 0; j < 4; ++j) Af[q * 4 + j] = -__expf(a[j]);
  }

  float h[16], Pp[16];
  if (PASS == 1) {
#pragma unroll
    for (int n = 0; n < 16; ++n) { h[n] = 0.f; Pp[n] = 1.f; }
  } else {
#pragma unroll
    for (int n = 0; n < 16; ++n)
      h[n] = Hin[(((size_t)bdir * NCH + ch) * 16 + n) * DI + d];
  }
  const float Dv = (PASS == 2) ? dpp[d] : 0.f;

  __syncthreads();

  float db[2][GP], xb[2][GP], zb[2][GP];
#define TLOAD(g, bu)                                                      \
  {                                                                       \
    _Pragma("unroll") for (int i = 0; i < GP; ++i) {                      \
      const size_t row = tb + t0 + (g) * GP + i;                          \
      db[bu][i] = bf2f(delta[row * DI + d]);                              \
      xb[bu][i] = bf2f(xc[row * DI + d]);                                 \
      if (PASS == 2) zb[bu][i] = bf2f(xz[row * (2 * DI) + DI + d]);       \
    }                                                                     \
  }
  TLOAD(0, 0)
#pragma unroll 1
  for (int g = 0; g < TCH / GP; ++g) {
    const int bu = g & 1;
    if (g + 1 < TCH / GP) TLOAD(g + 1, bu ^ 1)
#pragma unroll
    for (int i = 0; i < GP; ++i) {
      const int t = g * GP + i;
      const float dlt = db[bu][i];
      const float xcv = xb[bu][i];
      const float dbx = dlt * xcv;
      float yv = 0.f;
#pragma unroll
      for (int q = 0; q < 4; ++q) {
        const f32x4 B4 = *(const f32x4*)&sBC[t][q * 4];
        f32x4 C4;
        if (PASS == 2) C4 = *(const f32x4*)&sBC[t][16 + q * 4];
#pragma unroll
        for (int j = 0; j < 4; ++j) {
          const int n = q * 4 + j;
          const float dA = __expf(dlt * Af[n]);
          if (PASS == 1) Pp[n] *= dA;
          h[n] = fmaf(dA, h[n], B4[j] * dbx);
          if (PASS == 2) yv = fmaf(h[n], C4[j], yv);
        }
      }
      if (PASS == 2) {
        const float zv = zb[bu][i];
        const float sz = zv / (1.f + __expf(-zv));
        y[(tb + t0 + t) * DI + d] = f2bf((yv + xcv * Dv) * sz);
      }
    }
  }
#undef TLOAD

  if (PASS == 1) {
#pragma unroll
    for (int n = 0; n < 16; ++n) {
      const size_t o = (((size_t)bdir * NCH + ch) * 16 + n) * DI + d;
      Sb[o] = h[n];
      Pb[o] = Pp[n];
    }
  }
}

// combine: sequential over NCH chunks per (bdir,n,d); writes Hin.
__launch_bounds__(256)
__global__ void k_comb(const float* __restrict__ Sb, const float* __restrict__ Pb,
                       float* __restrict__ Hin) {
  const int gid = blockIdx.x * 256 + threadIdx.x;  // 64*1536
  const int d = gid % DI;
  const int bn = gid / DI;            // bdir*16 + n
  const int bdir = bn >> 4, n = bn & 15;
  float H = 0.f;
#pragma unroll
  for (int c = 0; c < NCH; ++c) {
    const size_t o = (((size_t)bdir * NCH + c) * 16 + n) * DI + d;
    Hin[o] = H;
    H = fmaf(Pb[o], H, Sb[o]);
  }
}

// ---------------- final: out = x + sum(out-proj slabs) + flip -------------
// goutP layout: dir0 slabs 0,1 then dir1 slabs 0,1, each [M_TOK x DM] fp32.
__launch_bounds__(256)
__global__ void k_final(const float* __restrict__ x, const float* __restrict__ gp,
                        float* __restrict__ out) {
  const int c = blockIdx.x * 256 + threadIdx.x;
  const int tok = blockIdx.y;
  const int ftok = tok ^ (L_SEQ - 1);
  const size_t i = (size_t)tok * DM + c;
  const size_t fi = (size_t)ftok * DM + c;
  const size_t S = (size_t)M_TOK * DM;
  out[i] = x[i] + (gp[i] + gp[S + i]) + (gp[2 * S + fi] + gp[3 * S + fi]);
}

extern "C" void kernel_launch(void* const* d_in, const int* in_sizes, int n_in,
                              void* d_out, int out_size, void* d_ws, size_t ws_size,
                              hipStream_t stream) {
  (void)n_in; (void)out_size; (void)in_sizes;
  const float* x      = (const float*)d_in[0];
  const float* ln_g   = (const float*)d_in[1];
  const float* ln_b   = (const float*)d_in[2];
  const float* in_w_f[2]  = {(const float*)d_in[3],  (const float*)d_in[12]};
  const float* conv_w[2]  = {(const float*)d_in[4],  (const float*)d_in[13]};
  const float* conv_b[2]  = {(const float*)d_in[5],  (const float*)d_in[14]};
  const float* xproj_w[2] = {(const float*)d_in[6],  (const float*)d_in[15]};
  const float* dt_w[2]    = {(const float*)d_in[7],  (const float*)d_in[16]};
  const float* dt_b[2]    = {(const float*)d_in[8],  (const float*)d_in[17]};
  const float* A_log[2]   = {(const float*)d_in[9],  (const float*)d_in[18]};
  const float* Dp[2]      = {(const float*)d_in[10], (const float*)d_in[19]};
  const float* out_w_f[2] = {(const float*)d_in[11], (const float*)d_in[20]};

  char* ws = (char*)d_ws;
  size_t off = 0;
  auto alloc = [&](size_t bytes) {
    void* p = ws + off;
    off = (off + bytes + 255) & ~(size_t)255;
    return p;
  };

  u16* inw[2];  for (int i = 0; i < 2; ++i) inw[i]  = (u16*)alloc((size_t)2 * DI * DM * 2);
  u16* outw[2]; for (int i = 0; i < 2; ++i) outw[i] = (u16*)alloc((size_t)DM * DI * 2);
  u16* x0 = (u16*)alloc((size_t)M_TOK * DM * 2);
  u16* xzb[2];    for (int i = 0; i < 2; ++i) xzb[i]  = (u16*)alloc((size_t)M_TOK * 2 * DI * 2);
  u16* xc[2];     for (int i = 0; i < 2; ++i) xc[i]   = (u16*)alloc((size_t)M_TOK * DI * 2);
  float* dbc[2];  for (int i = 0; i < 2; ++i) dbc[i]  = (float*)alloc((size_t)M_TOK * 128 * 4);
  u16* dtin[2];   for (int i = 0; i < 2; ++i) dtin[i] = (u16*)alloc((size_t)M_TOK * 64 * 2);
  u16* dltb[2];   for (int i = 0; i < 2; ++i) dltb[i] = (u16*)alloc((size_t)M_TOK * DI * 2);
  u16* yb[2];     for (int i = 0; i < 2; ++i) yb[i]   = (u16*)alloc((size_t)M_TOK * DI * 2);
  u16* xpw[2];    for (int i = 0; i < 2; ++i) xpw[i]  = (u16*)alloc((size_t)128 * DI * 2);
  u16* dtwp[2];   for (int i = 0; i < 2; ++i) dtwp[i] = (u16*)alloc((size_t)DI * 64 * 2);
  float* Sb  = (float*)alloc((size_t)4 * NCH * 16 * DI * 4);   // 12.58 MB
  float* Pb  = (float*)alloc((size_t)4 * NCH * 16 * DI * 4);   // 12.58 MB (contiguous after Sb)
  float* Hin = (float*)alloc((size_t)4 * NCH * 16 * DI * 4);

  // Aliases (disjoint lifetimes):
  //  xpp (x-proj partials, 2 dirs x 8 slabs x M x 128 fp32 = 16.8 MB) lives
  //    before scan -> aliases Sb..Pb (25.2 MB).
  //  goutP (out-proj partials, 2 dirs x 2 slabs x M x DM fp32 = 25.2 MB)
  //    lives after scan (Sb/Pb dead post-k_comb) -> same region.
  float* xpp   = Sb;
  float* goutP = Sb;

  if (off > ws_size) return;  // sentinel: zero output -> absmax 4.97 diag

  // ws entry state must be identical on every call (empirically required —
  // round 11 diverged post-timing without this).
  hipMemsetAsync(d_ws, 0, off, stream);

  for (int i = 0; i < 2; ++i) {
    k_cvt<<<dim3((2 * DI * DM + 255) / 256), dim3(256), 0, stream>>>(in_w_f[i], inw[i], 2 * DI * DM);
    k_cvt<<<dim3((DM * DI + 255) / 256), dim3(256), 0, stream>>>(out_w_f[i], outw[i], DM * DI);
  }

  k_ln<<<dim3(M_TOK), dim3(256), 0, stream>>>(x, ln_g, ln_b, x0);
  k_pad_xproj<<<dim3(6, 128, 2), dim3(256), 0, stream>>>(xproj_w[0], xproj_w[1], xpw[0], xpw[1]);
  k_pad_dtw<<<dim3(384, 2), dim3(256), 0, stream>>>(dt_w[0], dt_w[1], dtwp[0], dtwp[1]);
  // in-proj: xz = x0 @ in_w^T, bf16 out; BM=64 -> 1536 blocks (6/CU)
  k_gemm<64, 128, 1, 4, 3, 1><<<dim3(24, 32, 2), dim3(256), 0, stream>>>(
      x0, x0, inw[0], inw[1], nullptr, nullptr, nullptr, nullptr, xzb[0], xzb[1],
      2 * DI, DM, 1);
  k_conv<<<dim3(6, M_TOK, 2), dim3(256), 0, stream>>>(
      xzb[0], xzb[1], xc[0], xc[1], conv_w[0], conv_w[1], conv_b[0], conv_b[1]);
  // x-proj: split-K 8 partial slabs (512 blocks, Keff=192)
  k_gemm<64, 128, 1, 4, 4, 8><<<dim3(1, 32, 16), dim3(256), 0, stream>>>(
      xc[0], xc[1], xpw[0], xpw[1], xpp, xpp + (size_t)8 * M_TOK * 128,
      nullptr, nullptr, nullptr, nullptr, 128, DI, 0);
  k_xred<<<dim3(1024, 2), dim3(256), 0, stream>>>(xpp, dbc[0], dbc[1], dtin[0], dtin[1]);
  // dt-proj: delta = softplus(dtin @ dt_w^T + dt_b), bf16 out
  k_gemm<128, 128, 2, 2, 2, 1><<<dim3(12, 16, 2), dim3(256), 0, stream>>>(
      dtin[0], dtin[1], dtwp[0], dtwp[1], nullptr, nullptr, dt_b[0], dt_b[1],
      dltb[0], dltb[1], DI, 64, 0);
  // two-pass scan
  k_scan_pass<1><<<dim3(24, NCH, 4), dim3(64), 0, stream>>>(
      dltb[0], dltb[1], xc[0], xc[1], dbc[0], dbc[1], xzb[0], xzb[1],
      A_log[0], A_log[1], Dp[0], Dp[1], Sb, Pb, nullptr, nullptr, nullptr);
  k_comb<<<dim3(384), dim3(256), 0, stream>>>(Sb, Pb, Hin);
  k_scan_pass<2><<<dim3(24, NCH, 4), dim3(64), 0, stream>>>(
      dltb[0], dltb[1], xc[0], xc[1], dbc[0], dbc[1], xzb[0], xzb[1],
      A_log[0], A_log[1], Dp[0], Dp[1], Sb, Pb, Hin, yb[0], yb[1]);
  // out-proj: split-K 2 partial slabs, BM=BN=64 -> 1536 blocks (Keff=768)
  k_gemm<64, 64, 2, 2, 4, 2><<<dim3(12, 32, 4), dim3(256), 0, stream>>>(
      yb[0], yb[1], outw[0], outw[1], goutP, goutP + (size_t)2 * M_TOK * DM,
      nullptr, nullptr, nullptr, nullptr, DM, DI, 0);
  k_final<<<dim3(3, M_TOK), dim3(256), 0, stream>>>(x, goutP, (float*)d_out);
}